// Round 7
// baseline (667.019 us; speedup 1.0000x reference)
//
#include <hip/hip_runtime.h>

#define NN 100000
#define NE 1600000
#define F 128
#define SCAN_CHUNK 2048
#define NB_SCAN ((NN + SCAN_CHUNK - 1) / SCAN_CHUNK)   // 49
#define NBUCK ((NN + 255) >> 8)                         // 391 buckets of 256 nodes
#define EPB (NE / 256)                                  // 6250 edges per scatter block

typedef __bf16 bf16x8 __attribute__((ext_vector_type(8)));
typedef float  f32x4  __attribute__((ext_vector_type(4)));
typedef unsigned short ushort8v __attribute__((ext_vector_type(8)));
typedef unsigned short ushort4v __attribute__((ext_vector_type(4)));

__device__ inline float bf2f(unsigned short h) { return __uint_as_float(((unsigned int)h) << 16); }
__device__ inline unsigned short f2bf_rn(float f) {
    unsigned int u = __float_as_uint(f);
    return (unsigned short)((u + 0x7FFFu + ((u >> 16) & 1u)) >> 16);
}

// ---------------- CSR build ----------------
__global__ void k_hist(const int* __restrict__ dst, int* __restrict__ deg) {
    int stride = gridDim.x * blockDim.x;
    for (int e = blockIdx.x * blockDim.x + threadIdx.x; e < NE; e += stride)
        atomicAdd(&deg[dst[e]], 1);
}

__global__ void k_scan_part(const int* __restrict__ deg, int* __restrict__ partial) {
    __shared__ int sdata[256];
    int base = blockIdx.x * SCAN_CHUNK;
    int sum = 0;
    for (int j = threadIdx.x; j < SCAN_CHUNK; j += 256) {
        int idx = base + j;
        sum += (idx < NN) ? deg[idx] : 0;
    }
    sdata[threadIdx.x] = sum;
    __syncthreads();
    for (int s = 128; s > 0; s >>= 1) {
        if (threadIdx.x < s) sdata[threadIdx.x] += sdata[threadIdx.x + s];
        __syncthreads();
    }
    if (threadIdx.x == 0) partial[blockIdx.x] = sdata[0];
}

__global__ void k_scan_mid(int* __restrict__ partial) {
    if (threadIdx.x == 0) {
        int acc = 0;
        for (int i = 0; i < NB_SCAN; ++i) { int v = partial[i]; partial[i] = acc; acc += v; }
    }
}

__global__ void k_scan_final(const int* __restrict__ deg, const int* __restrict__ partial,
                             int* __restrict__ row_ptr, int* __restrict__ cursor) {
    __shared__ int svals[SCAN_CHUNK];
    __shared__ int ssum[256];
    int base = blockIdx.x * SCAN_CHUNK;
    for (int j = threadIdx.x; j < SCAN_CHUNK; j += 256) {
        int idx = base + j;
        svals[j] = (idx < NN) ? deg[idx] : 0;
    }
    __syncthreads();
    int t0 = threadIdx.x * 8;
    int loc[8];
    int s = 0;
#pragma unroll
    for (int k = 0; k < 8; ++k) { loc[k] = s; s += svals[t0 + k]; }
    ssum[threadIdx.x] = s;
    __syncthreads();
    for (int off = 1; off < 256; off <<= 1) {
        int v = (threadIdx.x >= off) ? ssum[threadIdx.x - off] : 0;
        __syncthreads();
        ssum[threadIdx.x] += v;
        __syncthreads();
    }
    int texcl = (threadIdx.x == 0) ? 0 : ssum[threadIdx.x - 1];
    int offbase = partial[blockIdx.x] + texcl;
#pragma unroll
    for (int k = 0; k < 8; ++k) {
        int idx = base + t0 + k;
        if (idx < NN) {
            int v = offbase + loc[k];
            row_ptr[idx] = v;
            cursor[idx]  = v;
        }
    }
    if (blockIdx.x == 0 && threadIdx.x == 0) row_ptr[NN] = NE;
}

__global__ void k_bcur(const int* __restrict__ row_ptr, int* __restrict__ bcur) {
    int t = blockIdx.x * 256 + threadIdx.x;
    if (t < NBUCK) bcur[t] = row_ptr[t << 8];
}

__global__ __launch_bounds__(256) void k_scatterA(const int* __restrict__ src,
                                                  const int* __restrict__ dst,
                                                  int* __restrict__ bcur,
                                                  uint2* __restrict__ scratch) {
    __shared__ uint2 sEdge[EPB];          // 50 KB
    __shared__ int cnt[512];
    __shared__ int scn[512];
    __shared__ int cntB[512];
    __shared__ int gbase[512];
    __shared__ int ssum[256];

    const int tid = threadIdx.x;
    const int ebase = blockIdx.x * EPB;

#pragma unroll
    for (int i = tid; i < 512; i += 256) { cnt[i] = 0; cntB[i] = 0; }
    __syncthreads();

    for (int i = tid; i < EPB; i += 256) {
        int b = dst[ebase + i] >> 8;
        atomicAdd(&cnt[b], 1);
    }
    __syncthreads();

    int c0 = cnt[2 * tid], c1 = cnt[2 * tid + 1];
    ssum[tid] = c0 + c1;
    __syncthreads();
    for (int off = 1; off < 256; off <<= 1) {
        int v = (tid >= off) ? ssum[tid - off] : 0;
        __syncthreads();
        ssum[tid] += v;
        __syncthreads();
    }
    int texcl = (tid == 0) ? 0 : ssum[tid - 1];
    scn[2 * tid] = texcl;
    scn[2 * tid + 1] = texcl + c0;
#pragma unroll
    for (int i = tid; i < NBUCK; i += 256) {
        int c = cnt[i];
        gbase[i] = c ? atomicAdd(&bcur[i], c) : 0;
    }
    __syncthreads();

    for (int i = tid; i < EPB; i += 256) {
        int s = src[ebase + i], d = dst[ebase + i];
        int b = d >> 8;
        int rank = atomicAdd(&cntB[b], 1);
        sEdge[scn[b] + rank] = make_uint2((unsigned)s, (unsigned)d);
    }
    __syncthreads();

    for (int i = tid; i < EPB; i += 256) {
        uint2 ed = sEdge[i];
        int b = (int)(ed.y >> 8);
        scratch[gbase[b] + (i - scn[b])] = ed;
    }
}

__global__ __launch_bounds__(256) void k_fillB(const int* __restrict__ row_ptr,
                                               const uint2* __restrict__ scratch,
                                               int* __restrict__ cursor,
                                               int* __restrict__ csr) {
    int b = blockIdx.x;
    int s = row_ptr[b << 8];
    int endNode = (b + 1) << 8; if (endNode > NN) endNode = NN;
    int e = row_ptr[endNode];
    for (int i = s + threadIdx.x; i < e; i += 256) {
        uint2 ed = scratch[i];
        int p = atomicAdd(&cursor[ed.y], 1);
        csr[p] = (int)ed.x;
    }
}

// ---------------- x -> bf16 (RTN) ----------------
__global__ void k_x2bf(const float* __restrict__ x, unsigned short* __restrict__ xb) {
    int idx = blockIdx.x * 256 + threadIdx.x;     // over float4s, NN*128/4 total
    float4 v = ((const float4*)x)[idx];
    ushort4v h;
    h.x = f2bf_rn(v.x);
    h.y = f2bf_rn(v.y);
    h.z = f2bf_rn(v.z);
    h.w = f2bf_rn(v.w);
    ((ushort4v*)xb)[idx] = h;
}

// ---------------- weight split: W[k][n] fp32 -> Wt_hi/Wt_lo [n][k] bf16 ----------------
struct WPack {
    const float* w[5];
    unsigned short* hi[5];
    unsigned short* lo[5];
};

__global__ void k_wsplit_all(WPack p) {
    int which = blockIdx.x >> 6;
    int idx = (blockIdx.x & 63) * 256 + threadIdx.x; // over n*128+k
    int n = idx >> 7, k = idx & 127;
    float v = p.w[which][k * 128 + n];
    unsigned short h = f2bf_rn(v);
    unsigned short l = f2bf_rn(v - bf2f(h));
    p.hi[which][idx] = h;
    p.lo[which][idx] = l;
}

// ---------------- fused layer: gather + 2-GEMM MLP ----------------
// Phase 1: u[r] = G[r] + sum_{j in N(r)} G[j] (fp32 acc) -> RTN bf16 -> swizzled LDS A-tile.
// Phase 2: GEMM1 (+relu) -> LDS -> GEMM2 -> H (bf16)   [L3: GEMM1 -> dot w32 -> out fp32]
template <int L3>
__global__ __launch_bounds__(256, 4) void k_layer(const unsigned short* __restrict__ G,
                                                  const int* __restrict__ row_ptr,
                                                  const int* __restrict__ csr,
                                                  const unsigned short* __restrict__ W1hi,
                                                  const unsigned short* __restrict__ W1lo,
                                                  const float* __restrict__ b1,
                                                  const unsigned short* __restrict__ W2hi,
                                                  const unsigned short* __restrict__ W2lo,
                                                  const float* __restrict__ b2,
                                                  const float* __restrict__ w32,
                                                  const float* __restrict__ b32,
                                                  unsigned short* __restrict__ H,
                                                  float* __restrict__ out) {
    __shared__ __align__(16) unsigned short sA[128 * 128];   // 32 KB

    const int tid = threadIdx.x;
    const int row0 = blockIdx.x * 128;
    const int wave = tid >> 6;
    const int lane = tid & 63;
    const int m16  = lane & 15;
    const int quad = lane >> 4;

    // ---- phase 1: gather into sA ----
    {
        const int grp = tid >> 5;        // 0..7
        const int l32 = tid & 31;
        const int lofs = l32 * 4;        // col base (4 bf16 per lane)
        const int c = lofs;
        const int u = c >> 3;            // granule
        for (int it = 0; it < 16; ++it) {
            int r = it * 8 + grp;        // 0..127
            int node = row0 + r;
            float a0 = 0.f, a1 = 0.f, a2 = 0.f, a3 = 0.f;
            if (node < NN) {
                ushort4v sh = *(const ushort4v*)&G[(size_t)node * F + lofs];
                a0 = bf2f(sh.x); a1 = bf2f(sh.y); a2 = bf2f(sh.z); a3 = bf2f(sh.w);
                int s = row_ptr[node], e = row_ptr[node + 1];
                int p = s;
                for (; p + 4 <= e; p += 4) {
                    int j0 = csr[p], j1 = csr[p + 1], j2 = csr[p + 2], j3 = csr[p + 3];
                    ushort4v v0 = *(const ushort4v*)&G[(size_t)j0 * F + lofs];
                    ushort4v v1 = *(const ushort4v*)&G[(size_t)j1 * F + lofs];
                    ushort4v v2 = *(const ushort4v*)&G[(size_t)j2 * F + lofs];
                    ushort4v v3 = *(const ushort4v*)&G[(size_t)j3 * F + lofs];
                    a0 += bf2f(v0.x) + bf2f(v1.x) + bf2f(v2.x) + bf2f(v3.x);
                    a1 += bf2f(v0.y) + bf2f(v1.y) + bf2f(v2.y) + bf2f(v3.y);
                    a2 += bf2f(v0.z) + bf2f(v1.z) + bf2f(v2.z) + bf2f(v3.z);
                    a3 += bf2f(v0.w) + bf2f(v1.w) + bf2f(v2.w) + bf2f(v3.w);
                }
                if (p + 2 <= e) {
                    int j0 = csr[p], j1 = csr[p + 1];
                    ushort4v v0 = *(const ushort4v*)&G[(size_t)j0 * F + lofs];
                    ushort4v v1 = *(const ushort4v*)&G[(size_t)j1 * F + lofs];
                    a0 += bf2f(v0.x) + bf2f(v1.x);
                    a1 += bf2f(v0.y) + bf2f(v1.y);
                    a2 += bf2f(v0.z) + bf2f(v1.z);
                    a3 += bf2f(v0.w) + bf2f(v1.w);
                    p += 2;
                }
                if (p < e) {
                    int j0 = csr[p];
                    ushort4v v0 = *(const ushort4v*)&G[(size_t)j0 * F + lofs];
                    a0 += bf2f(v0.x); a1 += bf2f(v0.y); a2 += bf2f(v0.z); a3 += bf2f(v0.w);
                }
            }
            ushort4v o;
            o.x = f2bf_rn(a0); o.y = f2bf_rn(a1); o.z = f2bf_rn(a2); o.w = f2bf_rn(a3);
            *(ushort4v*)&sA[r * 128 + ((u ^ (r & 15)) << 3) + (c & 7)] = o;
        }
    }
    __syncthreads();

    // ---- GEMM1 ----
    f32x4 acc[2][8] = {};
#pragma unroll
    for (int ks = 0; ks < 4; ++ks) {
        bf16x8 a[2];
#pragma unroll
        for (int rt = 0; rt < 2; ++rt) {
            int rowL = wave * 32 + rt * 16 + m16;
            int u = ks * 4 + quad;
            a[rt] = *(const bf16x8*)&sA[rowL * 128 + ((u ^ (rowL & 15)) << 3)];
        }
#pragma unroll
        for (int ct = 0; ct < 8; ++ct) {
            int widx = (ct * 16 + m16) * 128 + ks * 32 + quad * 8;
            bf16x8 bh = *(const bf16x8*)&W1hi[widx];
            bf16x8 bl = *(const bf16x8*)&W1lo[widx];
#pragma unroll
            for (int rt = 0; rt < 2; ++rt) {
                acc[rt][ct] = __builtin_amdgcn_mfma_f32_16x16x32_bf16(a[rt], bh, acc[rt][ct], 0, 0, 0);
                acc[rt][ct] = __builtin_amdgcn_mfma_f32_16x16x32_bf16(a[rt], bl, acc[rt][ct], 0, 0, 0);
            }
        }
    }

    if (L3) {
#pragma unroll
        for (int rt = 0; rt < 2; ++rt) {
            float s[4] = {0.f, 0.f, 0.f, 0.f};
#pragma unroll
            for (int ct = 0; ct < 8; ++ct) {
                int col = ct * 16 + m16;
                float bv = b1[col];
                float wv = w32[col];
#pragma unroll
                for (int i = 0; i < 4; ++i) {
                    float v = fmaxf(acc[rt][ct][i] + bv, 0.f);
                    s[i] += v * wv;
                }
            }
#pragma unroll
            for (int i = 0; i < 4; ++i) {
#pragma unroll
                for (int mask = 1; mask < 16; mask <<= 1)
                    s[i] += __shfl_xor(s[i], mask, 64);
            }
            if (m16 == 0) {
#pragma unroll
                for (int i = 0; i < 4; ++i) {
                    int row = row0 + wave * 32 + rt * 16 + quad * 4 + i;
                    if (row < NN) out[row] = s[i] + b32[0];
                }
            }
        }
        return;
    }

    // ---- h1 = relu(acc+b1) -> bf16 into LDS ----
    __syncthreads();
#pragma unroll
    for (int rt = 0; rt < 2; ++rt) {
#pragma unroll
        for (int ct = 0; ct < 8; ++ct) {
            int col = ct * 16 + m16;
            float bv = b1[col];
#pragma unroll
            for (int i = 0; i < 4; ++i) {
                int rowL = wave * 32 + rt * 16 + quad * 4 + i;
                float v = fmaxf(acc[rt][ct][i] + bv, 0.f);
                sA[rowL * 128 + (((col >> 3) ^ (rowL & 15)) << 3) + (col & 7)] = f2bf_rn(v);
            }
        }
    }
    __syncthreads();

    // ---- GEMM2 ----
    f32x4 acc2[2][8] = {};
#pragma unroll
    for (int ks = 0; ks < 4; ++ks) {
        bf16x8 a[2];
#pragma unroll
        for (int rt = 0; rt < 2; ++rt) {
            int rowL = wave * 32 + rt * 16 + m16;
            int u = ks * 4 + quad;
            a[rt] = *(const bf16x8*)&sA[rowL * 128 + ((u ^ (rowL & 15)) << 3)];
        }
#pragma unroll
        for (int ct = 0; ct < 8; ++ct) {
            int widx = (ct * 16 + m16) * 128 + ks * 32 + quad * 8;
            bf16x8 bh = *(const bf16x8*)&W2hi[widx];
            bf16x8 bl = *(const bf16x8*)&W2lo[widx];
#pragma unroll
            for (int rt = 0; rt < 2; ++rt) {
                acc2[rt][ct] = __builtin_amdgcn_mfma_f32_16x16x32_bf16(a[rt], bh, acc2[rt][ct], 0, 0, 0);
                acc2[rt][ct] = __builtin_amdgcn_mfma_f32_16x16x32_bf16(a[rt], bl, acc2[rt][ct], 0, 0, 0);
            }
        }
    }

    // ---- epilogue: bias -> bf16 -> LDS -> coalesced store ----
    __syncthreads();
#pragma unroll
    for (int rt = 0; rt < 2; ++rt) {
#pragma unroll
        for (int ct = 0; ct < 8; ++ct) {
            int col = ct * 16 + m16;
            float bv = b2[col];
#pragma unroll
            for (int i = 0; i < 4; ++i) {
                int rowL = wave * 32 + rt * 16 + quad * 4 + i;
                float v = acc2[rt][ct][i] + bv;
                sA[rowL * 128 + (((col >> 3) ^ (rowL & 15)) << 3) + (col & 7)] = f2bf_rn(v);
            }
        }
    }
    __syncthreads();
    {
        ushort8v* go = (ushort8v*)(H + (size_t)row0 * F);
#pragma unroll
        for (int i = 0; i < 8; ++i) {
            int fg = i * 256 + tid;
            int r = fg >> 4, u = fg & 15;
            if (row0 + r < NN)
                go[fg] = *(const ushort8v*)&sA[r * 128 + ((u ^ (r & 15)) << 3)];
        }
    }
}

// ---------------- launch ----------------
static inline size_t align256(size_t x) { return (x + 255) & ~(size_t)255; }

extern "C" void kernel_launch(void* const* d_in, const int* in_sizes, int n_in,
                              void* d_out, int out_size, void* d_ws, size_t ws_size,
                              hipStream_t stream) {
    const float* x   = (const float*)d_in[0];
    const int*   ei  = (const int*)d_in[1];
    const float* w11 = (const float*)d_in[2];
    const float* b11 = (const float*)d_in[3];
    const float* w12 = (const float*)d_in[4];
    const float* b12 = (const float*)d_in[5];
    const float* w21 = (const float*)d_in[6];
    const float* b21 = (const float*)d_in[7];
    const float* w22 = (const float*)d_in[8];
    const float* b22 = (const float*)d_in[9];
    const float* w31 = (const float*)d_in[10];
    const float* b31 = (const float*)d_in[11];
    const float* w32 = (const float*)d_in[12];
    const float* b32 = (const float*)d_in[13];
    float* out = (float*)d_out;

    const int* src = ei;
    const int* dst = ei + NE;

    char* ws = (char*)d_ws;
    size_t off = 0;
    unsigned short* Abuf = (unsigned short*)(ws + off); off += align256((size_t)NN * F * 2);
    unsigned short* Bbuf = (unsigned short*)(ws + off); off += align256((size_t)NN * F * 2);
    int* deg     = (int*)(ws + off); off += align256((size_t)NN * 4);
    int* row_ptr = (int*)(ws + off); off += align256((size_t)(NN + 1) * 4);
    int* cursor  = (int*)(ws + off); off += align256((size_t)NN * 4);
    int* partial = (int*)(ws + off); off += align256((size_t)NB_SCAN * 4);
    int* bcur    = (int*)(ws + off); off += align256((size_t)NBUCK * 4);
    int* csr     = (int*)(ws + off); off += align256((size_t)NE * 4);
    uint2* scratch = (uint2*)(ws + off); off += align256((size_t)NE * 8);
    unsigned short* whi[5];
    unsigned short* wlo[5];
    for (int i = 0; i < 5; ++i) {
        whi[i] = (unsigned short*)(ws + off); off += align256((size_t)128 * 128 * 2);
        wlo[i] = (unsigned short*)(ws + off); off += align256((size_t)128 * 128 * 2);
    }
    (void)ws_size;

    // ---- weight + input conversion ----
    WPack wp;
    wp.w[0] = w11; wp.w[1] = w12; wp.w[2] = w21; wp.w[3] = w22; wp.w[4] = w31;
    for (int i = 0; i < 5; ++i) { wp.hi[i] = whi[i]; wp.lo[i] = wlo[i]; }
    k_wsplit_all<<<320, 256, 0, stream>>>(wp);
    k_x2bf<<<(NN * F / 4 + 255) / 256, 256, 0, stream>>>(x, Abuf);

    // ---- CSR build ----
    (void)hipMemsetAsync(deg, 0, (size_t)NN * 4, stream);
    k_hist<<<2048, 256, 0, stream>>>(dst, deg);
    k_scan_part<<<NB_SCAN, 256, 0, stream>>>(deg, partial);
    k_scan_mid<<<1, 64, 0, stream>>>(partial);
    k_scan_final<<<NB_SCAN, 256, 0, stream>>>(deg, partial, row_ptr, cursor);
    k_bcur<<<(NBUCK + 255) / 256, 256, 0, stream>>>(row_ptr, bcur);
    k_scatterA<<<256, 256, 0, stream>>>(src, dst, bcur, scratch);
    k_fillB<<<NBUCK, 256, 0, stream>>>(row_ptr, scratch, cursor, csr);

    const int layerBlocks = (NN + 127) / 128;

    // ---- layer 1: Abuf -> Bbuf ----
    k_layer<0><<<layerBlocks, 256, 0, stream>>>(Abuf, row_ptr, csr,
                                                whi[0], wlo[0], b11, whi[1], wlo[1], b12,
                                                nullptr, nullptr, Bbuf, nullptr);
    // ---- layer 2: Bbuf -> Abuf ----
    k_layer<0><<<layerBlocks, 256, 0, stream>>>(Bbuf, row_ptr, csr,
                                                whi[2], wlo[2], b21, whi[3], wlo[3], b22,
                                                nullptr, nullptr, Abuf, nullptr);
    // ---- layer 3: Abuf -> out ----
    k_layer<1><<<layerBlocks, 256, 0, stream>>>(Abuf, row_ptr, csr,
                                                whi[4], wlo[4], b31, nullptr, nullptr, nullptr,
                                                w32, b32, nullptr, out);
}